// Round 1
// 68.670 us; speedup vs baseline: 1.0214x; 1.0214x over previous
//
#include <hip/hip_runtime.h>
#include <hip/hip_bf16.h>

#define B_DIM 16
#define T_DIM 128
#define R_DIM 2048
#define ABITS 20
#define VBITS 32
#define RPB   32                       // reads per block
#define BLOCKS_PER_B (R_DIM / RPB)     // 64
#define TBL_STRIDE 512                 // u32 words per batch table in d_ws

// ---------------------------------------------------------------------------
// Two-kernel split (was: every block redundantly rebuilt its batch's table).
//
// build_kernel (16 blocks): decode writes, dedup (first-occurrence -> slot,
//   last write -> value), bit-transpose values, emit compact per-batch table
//   to workspace:  [0..128) keys  [128..256) valT (bit j word w at 128+j*4+w)
//   [256] n.  1 KB/batch -> 16 KB total, L2-resident for the read kernel.
//
// read_kernel (1024 blocks, 256 thr): 8 threads per read; thread k owns
//   entries [16k,16k+16) and output bits [4k,4k+4).
//   - table + 32 read-addr encodings staged once per block (1 sync total)
//   - read addr decoded via 5 float4 LDS reads (was 20 scalar)
//   - 16 distances kept in REGISTERS (static indices only) -> tie mask is
//     16 compares, no second key pass
//   - block-uniform n==128 fast path drops all validity selects (collisions
//     in 128 random 20-bit addrs are ~0.8%/batch; slow path keeps exactness)
//   - exp-free softmax: tail weight e^-20 ~ 2e-9 dropped; out = mean of +-1
//     bits over min-Hamming-distance entries via popc against transposed vals
// ---------------------------------------------------------------------------

__global__ __launch_bounds__(256) void build_kernel(
    const float* __restrict__ waddr,   // [B,T,20]
    const float* __restrict__ wval,    // [B,T,32]
    unsigned* __restrict__ tbl)        // [B,TBL_STRIDE]
{
    const int b = blockIdx.x;
    const int t = threadIdx.x;

    __shared__ unsigned s_addr[T_DIM];
    __shared__ unsigned s_val[T_DIM];
    __shared__ unsigned s_key[T_DIM];
    __shared__ unsigned s_vbits[T_DIM];
    __shared__ int      s_slotmap[T_DIM];
    __shared__ int      s_n;

    if (t == 0) s_n = 0;
    if (t < T_DIM) { s_key[t] = 0u; s_vbits[t] = 0u; }   // determinism for slots >= n

    // Decode write addresses (threads 0-127) and write values (threads 128-255).
    if (t < T_DIM) {
        const float4* ap = (const float4*)(waddr + (size_t)(b * T_DIM + t) * ABITS);
        unsigned a = 0;
        #pragma unroll
        for (int q = 0; q < ABITS / 4; ++q) {
            float4 f = ap[q];
            a |= (unsigned)(f.x > 0.f) << (4 * q + 0);
            a |= (unsigned)(f.y > 0.f) << (4 * q + 1);
            a |= (unsigned)(f.z > 0.f) << (4 * q + 2);
            a |= (unsigned)(f.w > 0.f) << (4 * q + 3);
        }
        s_addr[t] = a;
    } else {
        const int tv = t - T_DIM;
        const float4* vp = (const float4*)(wval + (size_t)(b * T_DIM + tv) * VBITS);
        unsigned v = 0;
        #pragma unroll
        for (int q = 0; q < VBITS / 4; ++q) {
            float4 f = vp[q];
            v |= (unsigned)(f.x > 0.f) << (4 * q + 0);
            v |= (unsigned)(f.y > 0.f) << (4 * q + 1);
            v |= (unsigned)(f.z > 0.f) << (4 * q + 2);
            v |= (unsigned)(f.w > 0.f) << (4 * q + 3);
        }
        s_val[tv] = v;
    }
    __syncthreads();

    // Dedup scan: first/last/first-index in one pass (threads < 128).
    int lastc = 0, t0 = t;
    if (t < T_DIM) {
        const unsigned a = s_addr[t];
        int firstc = 0;
        const uint4* a4 = (const uint4*)s_addr;
        #pragma unroll 8
        for (int u4 = 0; u4 < T_DIM / 4; ++u4) {
            uint4 kk = a4[u4];
            int u = u4 * 4;
            int e0 = (kk.x == a), e1 = (kk.y == a), e2 = (kk.z == a), e3 = (kk.w == a);
            firstc |= (e0 & (u + 0 < t)) | (e1 & (u + 1 < t)) | (e2 & (u + 2 < t)) | (e3 & (u + 3 < t));
            lastc  |= (e0 & (u + 0 > t)) | (e1 & (u + 1 > t)) | (e2 & (u + 2 > t)) | (e3 & (u + 3 > t));
            t0 = (e0 && (u + 0 < t0)) ? (u + 0) : t0;
            t0 = (e1 && (u + 1 < t0)) ? (u + 1) : t0;
            t0 = (e2 && (u + 2 < t0)) ? (u + 2) : t0;
            t0 = (e3 && (u + 3 < t0)) ? (u + 3) : t0;
        }
        if (!firstc) {                       // first occurrence -> owns a slot
            int slot = atomicAdd(&s_n, 1);   // order-free (softmax sum is order-invariant)
            s_key[slot] = a;
            s_slotmap[t] = slot;
        }
    }
    __syncthreads();
    if (t < T_DIM && !lastc)                 // last write to this addr -> value
        s_vbits[s_slotmap[t0]] = s_val[t];
    __syncthreads();

    // Bit-transpose values and emit the compact table.
    unsigned* dst = tbl + (size_t)b * TBL_STRIDE;
    if (t < 128) {
        const int j = t & 31, w = t >> 5;
        unsigned word = 0;
        #pragma unroll 8
        for (int i = 0; i < 32; ++i)
            word |= ((s_vbits[w * 32 + i] >> j) & 1u) << i;
        dst[128 + j * 4 + w] = word;
        dst[t] = s_key[t];
    }
    if (t == 0) dst[256] = (unsigned)s_n;
}

__global__ __launch_bounds__(256) void read_kernel(
    const unsigned* __restrict__ tbl,  // [B,TBL_STRIDE]
    const float* __restrict__ raddr,   // [B,R,20]
    float* __restrict__ out)           // [B,R,32]
{
    const int b    = blockIdx.x / BLOCKS_PER_B;
    const int rblk = blockIdx.x % BLOCKS_PER_B;
    const int t    = threadIdx.x;

    __shared__ unsigned s_key[T_DIM];
    __shared__ unsigned s_valT[VBITS * 4];
    __shared__ float    s_f[RPB * ABITS];
    __shared__ int      s_n;

    // Stage the compact table (64 dwordx4 loads, L2-hit) + read addrs (160 float4).
    const unsigned* tb = tbl + (size_t)b * TBL_STRIDE;
    if (t < 32)                ((uint4*)s_key)[t]       = ((const uint4*)tb)[t];
    else if (t < 64)           ((uint4*)s_valT)[t - 32] = ((const uint4*)tb)[t];
    if (t == 0) s_n = (int)tb[256];

    const float4* rp = (const float4*)(raddr + ((size_t)b * R_DIM + (size_t)rblk * RPB) * ABITS);
    if (t < RPB * ABITS / 4) ((float4*)s_f)[t] = rp[t];
    __syncthreads();

    const int n  = s_n;
    const int rl = t >> 3;     // local read 0..31
    const int k  = t & 7;      // my entry-group / output-bit-group

    // Decode my read address: 5 float4 LDS reads (rl*80 B, 16B-aligned).
    const float4* f4 = (const float4*)(s_f + rl * ABITS);
    unsigned ra = 0;
    #pragma unroll
    for (int q = 0; q < ABITS / 4; ++q) {
        float4 f = f4[q];
        ra |= (unsigned)(f.x > 0.f) << (4 * q + 0);
        ra |= (unsigned)(f.y > 0.f) << (4 * q + 1);
        ra |= (unsigned)(f.z > 0.f) << (4 * q + 2);
        ra |= (unsigned)(f.w > 0.f) << (4 * q + 3);
    }

    // Distances for my 16 entries, kept in registers (static indices only).
    int d[16];
    const uint4* k4 = (const uint4*)s_key;
    if (n == T_DIM) {          // block-uniform fast path: all slots valid
        #pragma unroll
        for (int j = 0; j < 4; ++j) {
            uint4 kk = k4[k * 4 + j];
            d[4 * j + 0] = __popc(kk.x ^ ra);
            d[4 * j + 1] = __popc(kk.y ^ ra);
            d[4 * j + 2] = __popc(kk.z ^ ra);
            d[4 * j + 3] = __popc(kk.w ^ ra);
        }
    } else {
        #pragma unroll
        for (int j = 0; j < 4; ++j) {
            uint4 kk = k4[k * 4 + j];
            const int e = k * 16 + j * 4;
            d[4 * j + 0] = __popc(kk.x ^ ra) | ((e + 0 >= n) ? 64 : 0);
            d[4 * j + 1] = __popc(kk.y ^ ra) | ((e + 1 >= n) ? 64 : 0);
            d[4 * j + 2] = __popc(kk.z ^ ra) | ((e + 2 >= n) ? 64 : 0);
            d[4 * j + 3] = __popc(kk.w ^ ra) | ((e + 3 >= n) ? 64 : 0);
        }
    }

    // Min tree + merge across the 8 lanes of this read.
    int dmin = min(min(min(d[0], d[1]), min(d[2], d[3])),
                   min(min(d[4], d[5]), min(d[6], d[7])));
    dmin = min(dmin, min(min(min(d[8],  d[9]),  min(d[10], d[11])),
                         min(min(d[12], d[13]), min(d[14], d[15]))));
    dmin = min(dmin, __shfl_xor(dmin, 1, 8));
    dmin = min(dmin, __shfl_xor(dmin, 2, 8));
    dmin = min(dmin, __shfl_xor(dmin, 4, 8));

    // Tie mask straight from registers (no second key pass).
    unsigned mask = 0;
    #pragma unroll
    for (int i = 0; i < 16; ++i)
        mask |= (unsigned)(d[i] == dmin) << i;

    // Assemble the full 128-entry match mask from the 8 lanes' 16-bit pieces.
    unsigned m0 = (unsigned)__shfl((int)mask, 0, 8) | ((unsigned)__shfl((int)mask, 1, 8) << 16);
    unsigned m1 = (unsigned)__shfl((int)mask, 2, 8) | ((unsigned)__shfl((int)mask, 3, 8) << 16);
    unsigned m2 = (unsigned)__shfl((int)mask, 4, 8) | ((unsigned)__shfl((int)mask, 5, 8) << 16);
    unsigned m3 = (unsigned)__shfl((int)mask, 6, 8) | ((unsigned)__shfl((int)mask, 7, 8) << 16);

    const int nm = __popc(m0) + __popc(m1) + __popc(m2) + __popc(m3);
    const float fn = (float)nm, inv = 1.0f / fn;
    const uint4* vT = (const uint4*)s_valT;
    float o[4];
    #pragma unroll
    for (int jj = 0; jj < 4; ++jj) {
        uint4 vt = vT[4 * k + jj];   // valT row for bit j = 4k+jj
        int ones = __popc(m0 & vt.x) + __popc(m1 & vt.y) + __popc(m2 & vt.z) + __popc(m3 & vt.w);
        o[jj] = (2.0f * (float)ones - fn) * inv;
    }
    float4* op = (float4*)(out + (((size_t)b * R_DIM + (size_t)rblk * RPB + rl) * VBITS + k * 4));
    *op = make_float4(o[0], o[1], o[2], o[3]);
}

extern "C" void kernel_launch(void* const* d_in, const int* in_sizes, int n_in,
                              void* d_out, int out_size, void* d_ws, size_t ws_size,
                              hipStream_t stream) {
    const float* waddr = (const float*)d_in[0]; // [16,128,20]
    const float* wval  = (const float*)d_in[1]; // [16,128,32]
    const float* raddr = (const float*)d_in[2]; // [16,2048,20]
    float* out = (float*)d_out;                 // [16,2048,32]
    unsigned* tbl = (unsigned*)d_ws;            // 16 * 512 u32 = 32 KB

    build_kernel<<<B_DIM, 256, 0, stream>>>(waddr, wval, tbl);
    read_kernel<<<B_DIM * BLOCKS_PER_B, 256, 0, stream>>>(tbl, raddr, out);
}